// Round 4
// baseline (633.236 us; speedup 1.0000x reference)
//
#include <hip/hip_runtime.h>
#include <hip/hip_cooperative_groups.h>

namespace cg = cooperative_groups;

typedef unsigned long long ull;
typedef __attribute__((ext_vector_type(8))) short bf16x8;
typedef __attribute__((ext_vector_type(4))) float f32x4;
typedef __attribute__((ext_vector_type(8))) unsigned short u16x8;

#define DECAY 0.99f
#define BETA 0.25f
#define EPSV 1e-5f
#define EPSGAP 0.0625f

// z: [32, 256, 32, 32] fp32 ; embedding: [1024, 256] ; N = 32*32*32 = 32768
#define Dd 256
#define Kk 1024
#define Nn 32768
#define ZELEM 8388608

__device__ __forceinline__ unsigned short f2bf(float f) {
    unsigned int x = __float_as_uint(f);
    x += 0x7FFFu + ((x >> 16) & 1u);          // RNE
    return (unsigned short)(x >> 16);
}
__device__ __forceinline__ float bf2f(unsigned short b) {
    return __uint_as_float(((unsigned int)b) << 16);
}
__device__ __forceinline__ unsigned mono(unsigned b) {
    return b ^ (((int)b >> 31) | 0x80000000u);   // monotone float->uint
}
__device__ __forceinline__ float unmono(unsigned m) {
    unsigned b = (m & 0x80000000u) ? (m ^ 0x80000000u) : ~m;
    return __uint_as_float(b);
}
__device__ __forceinline__ unsigned umin32(unsigned a, unsigned b) { return a < b ? a : b; }
__device__ __forceinline__ unsigned umax32(unsigned a, unsigned b) { return a > b ? a : b; }

// ---------------------------------------------------------------------------
// Kernel 1: pre-split embedding into MFMA-B-fragment order (hi/lo bf16),
// compute esq; zero hist / flagcnt / loss_fix / dw. 64 blocks.
__global__ __launch_bounds__(256) void prep_e_kernel(
        const float* __restrict__ emb, unsigned short* __restrict__ ehg,
        unsigned short* __restrict__ elg, float* __restrict__ esq,
        int* __restrict__ hist, int* __restrict__ flagcnt,
        float* __restrict__ loss_fix, float* __restrict__ dw) {
    const int nsub = blockIdx.x;
    const int t = threadIdx.x;
    if (t < 16) hist[nsub * 16 + t] = 0;
    if (nsub == 0 && t == 16) flagcnt[0] = 0;
    if (nsub == 0 && t == 17) loss_fix[0] = 0.0f;
    {
        float4* dwp = (float4*)dw;
        #pragma unroll
        for (int j = 0; j < 4; ++j)
            dwp[(size_t)(nsub * 256 + t) * 4 + j] = make_float4(0.f, 0.f, 0.f, 0.f);
    }
    #pragma unroll
    for (int it = 0; it < 2; ++it) {
        const int item = it * 256 + t;
        const int kc = item >> 6, lane = item & 63;
        const int quad = lane >> 4, nl = lane & 15;
        const float* ep = emb + (size_t)(nsub * 16 + nl) * Dd + kc * 32 + quad * 8;
        const float4 a = *(const float4*)ep;
        const float4 b4 = *(const float4*)(ep + 4);
        const float v[8] = {a.x, a.y, a.z, a.w, b4.x, b4.y, b4.z, b4.w};
        u16x8 hi, lo;
        #pragma unroll
        for (int j = 0; j < 8; ++j) {
            const unsigned short h = f2bf(v[j]);
            hi[j] = h;
            lo[j] = f2bf(v[j] - bf2f(h));
        }
        const size_t off = ((size_t)(nsub * 8 + kc) * 64 + lane) * 8;
        *(u16x8*)&ehg[off] = hi;
        *(u16x8*)&elg[off] = lo;
    }
    {
        const int nl = t >> 4, seg = t & 15;
        const float* ep = emb + (size_t)(nsub * 16 + nl) * Dd + seg * 16;
        float s = 0.0f;
        #pragma unroll
        for (int j = 0; j < 4; ++j) {
            const float4 v4 = *(const float4*)(ep + j * 4);
            s += v4.x * v4.x + v4.y * v4.y + v4.z * v4.z + v4.w * v4.w;
        }
        #pragma unroll
        for (int d = 1; d < 16; d <<= 1) s += __shfl_xor(s, d);
        if (seg == 0) esq[nsub * 16 + nl] = s;
    }
}

// ---------------------------------------------------------------------------
// Kernel 2: MFMA distance + top-2 argmin + hist + loss. 512 blocks x
// 64 points x all 1024 codes; 3-pass bf16 error-corrected GEMM.
// R1: fused transpose (zf written from staged regs) + T5 setprio.
// R3: A-frag dbuf (null — compiler already hoisted; kept, harmless).
// Occupancy pinned at 2 blocks/CU by LDS(70KB) and VGPR(204): micro-
// scheduling changes were null twice — leave the loop alone.
__global__ __launch_bounds__(256) void dist_kernel(
        const float* __restrict__ z, const unsigned short* __restrict__ ehg,
        const unsigned short* __restrict__ elg, const float* __restrict__ esq,
        float* __restrict__ zf,
        int* __restrict__ idx_i, float* __restrict__ idx_f,
        int* __restrict__ hist, int* __restrict__ flagcnt,
        int* __restrict__ flaglist, float* __restrict__ flagval,
        float* __restrict__ loss_p) {
    __shared__ __align__(16) unsigned short zh[64 * 256];   // 32KB
    __shared__ __align__(16) unsigned short zl[64 * 256];   // 32KB
    __shared__ ull mb[4][64], ms[4][64];                    // 4KB
    __shared__ float zsqp[256];                             // 1KB

    const int t = threadIdx.x, w = t >> 6, L = t & 63;
    const int quad = L >> 4, lr = L & 15;
    const int m0 = blockIdx.x * 64;
    const int b = m0 >> 10, hw0 = m0 & 1023;

    {
        const int c0 = w * 64;
        const float* zp = z + (size_t)b * 262144 + hw0 + L;
        float* zfp = zf + (size_t)(m0 + L) * 256 + c0;
        float s = 0.0f;
        #pragma unroll
        for (int cg = 0; cg < 8; ++cg) {
            float v[8];
            #pragma unroll
            for (int j = 0; j < 8; ++j)
                v[j] = zp[(size_t)(c0 + cg * 8 + j) * 1024];
            *(float4*)(zfp + cg * 8)     = make_float4(v[0], v[1], v[2], v[3]);
            *(float4*)(zfp + cg * 8 + 4) = make_float4(v[4], v[5], v[6], v[7]);
            u16x8 hi, lo;
            #pragma unroll
            for (int j = 0; j < 8; ++j) {
                s = fmaf(v[j], v[j], s);
                const unsigned short h = f2bf(v[j]);
                hi[j] = h;
                lo[j] = f2bf(v[j] - bf2f(h));
            }
            const int chunk = ((c0 >> 3) + cg) ^ (L & 7);
            *(u16x8*)&zh[L * 256 + chunk * 8] = hi;
            *(u16x8*)&zl[L * 256 + chunk * 8] = lo;
        }
        zsqp[L * 4 + w] = s;
    }
    __syncthreads();

    const unsigned short* ehw = ehg + (size_t)(w * 1024 + L) * 8;
    const unsigned short* elw = elg + (size_t)(w * 1024 + L) * 8;

    unsigned bb[16], ss[16];
    #pragma unroll
    for (int i = 0; i < 16; ++i) { bb[i] = 0xFFFFFFFFu; ss[i] = 0xFFFFFFFFu; }

    bf16x8 Bh[2][2], Bl[2][2];
    #pragma unroll
    for (int ni = 0; ni < 2; ++ni) {
        Bh[0][ni] = *(const bf16x8*)(ehw + (size_t)ni * 4096);
        Bl[0][ni] = *(const bf16x8*)(elw + (size_t)ni * 4096);
    }
    bf16x8 Ah[2][4], Al[2][4];
    #pragma unroll
    for (int mi = 0; mi < 4; ++mi) {
        const int chunk = quad ^ (lr & 7);               // kc = 0
        const int o = (mi * 16 + lr) * 256 + chunk * 8;
        Ah[0][mi] = *(const bf16x8*)&zh[o];
        Al[0][mi] = *(const bf16x8*)&zl[o];
    }

    for (int nt = 0; nt < 8; ++nt) {
        f32x4 acc[4][2];
        #pragma unroll
        for (int mi = 0; mi < 4; ++mi)
            #pragma unroll
            for (int ni = 0; ni < 2; ++ni) acc[mi][ni] = (f32x4){0.f, 0.f, 0.f, 0.f};

        #pragma unroll
        for (int kc = 0; kc < 8; ++kc) {
            const int cur = kc & 1, nxt = cur ^ 1;
            const int nkc = (kc + 1) & 7;
            const int nnt = (kc == 7) ? ((nt + 1) & 7) : nt;
            #pragma unroll
            for (int ni = 0; ni < 2; ++ni) {
                const size_t o = (size_t)nnt * 32768 + (size_t)ni * 4096 + (size_t)nkc * 512;
                Bh[nxt][ni] = *(const bf16x8*)(ehw + o);
                Bl[nxt][ni] = *(const bf16x8*)(elw + o);
            }
            #pragma unroll
            for (int mi = 0; mi < 4; ++mi) {
                const int chunk = (nkc * 4 + quad) ^ (lr & 7);
                const int o = (mi * 16 + lr) * 256 + chunk * 8;
                Ah[nxt][mi] = *(const bf16x8*)&zh[o];
                Al[nxt][mi] = *(const bf16x8*)&zl[o];
            }
            __builtin_amdgcn_s_setprio(1);
            #pragma unroll
            for (int mi = 0; mi < 4; ++mi)
                #pragma unroll
                for (int ni = 0; ni < 2; ++ni) {
                    acc[mi][ni] = __builtin_amdgcn_mfma_f32_16x16x32_bf16(Ah[cur][mi], Bh[cur][ni], acc[mi][ni], 0, 0, 0);
                    acc[mi][ni] = __builtin_amdgcn_mfma_f32_16x16x32_bf16(Ah[cur][mi], Bl[cur][ni], acc[mi][ni], 0, 0, 0);
                    acc[mi][ni] = __builtin_amdgcn_mfma_f32_16x16x32_bf16(Al[cur][mi], Bh[cur][ni], acc[mi][ni], 0, 0, 0);
                }
            __builtin_amdgcn_s_setprio(0);
        }
        const int q0 = nt * 8 + w * 2;
        const float e0b = esq[q0 * 16 + lr] + 512.0f;
        const float e1b = esq[(q0 + 1) * 16 + lr] + 512.0f;
        #pragma unroll
        for (int mi = 0; mi < 4; ++mi)
            #pragma unroll
            for (int reg = 0; reg < 4; ++reg) {
                const int i = mi * 4 + reg;
                #pragma unroll
                for (int ni = 0; ni < 2; ++ni) {
                    const float val = fmaf(-2.0f, acc[mi][ni][reg], ni ? e1b : e0b);
                    const unsigned pk = (__float_as_uint(val) & 0xFFFFFFC0u) | (unsigned)(q0 + ni);
                    const unsigned mx = umax32(bb[i], pk);
                    bb[i] = umin32(bb[i], pk);
                    ss[i] = umin32(ss[i], mx);
                }
            }
    }

    #pragma unroll
    for (int mi = 0; mi < 4; ++mi)
        #pragma unroll
        for (int reg = 0; reg < 4; ++reg) {
            const int i = mi * 4 + reg;
            ull b2 = ((ull)(bb[i] & 0xFFFFFFC0u) << 14) | (ull)((bb[i] & 63u) * 16 + lr);
            ull s2 = ((ull)(ss[i] & 0xFFFFFFC0u) << 14) | (ull)((ss[i] & 63u) * 16 + lr);
            #pragma unroll
            for (int d = 1; d < 16; d <<= 1) {
                const ull ob = __shfl_xor(b2, d);
                const ull os = __shfl_xor(s2, d);
                const ull mx = ob < b2 ? b2 : ob;
                b2 = ob < b2 ? ob : b2;
                const ull ns = os < s2 ? os : s2;
                s2 = mx < ns ? mx : ns;
            }
            if (lr == 0) {
                const int row = mi * 16 + quad * 4 + reg;
                mb[w][row] = b2;
                ms[w][row] = s2;
            }
        }
    __syncthreads();

    if (t < 64) {
        ull b2 = mb[0][t], s2 = ms[0][t];
        #pragma unroll
        for (int ww = 1; ww < 4; ++ww) {
            const ull ob = mb[ww][t], os = ms[ww][t];
            const ull mx = ob < b2 ? b2 : ob;
            b2 = ob < b2 ? ob : b2;
            const ull ns = os < s2 ? os : s2;
            s2 = mx < ns ? mx : ns;
        }
        const int k = (int)(b2 & 16383ull);
        const float v1 = __uint_as_float((unsigned)(b2 >> 14)) - 512.0f;
        const float v2 = __uint_as_float((unsigned)(s2 >> 14)) - 512.0f;
        idx_i[m0 + t] = k;
        idx_f[m0 + t] = (float)k;
        atomicAdd(&hist[k], 1);
        if (v2 - v1 < EPSGAP) {
            const int pos = atomicAdd(flagcnt, 1);
            flaglist[pos] = m0 + t;
            flagval[pos] = v1;
        }
        float lp = v1 + zsqp[t * 4] + zsqp[t * 4 + 1] + zsqp[t * 4 + 2] + zsqp[t * 4 + 3];
        #pragma unroll
        for (int d = 32; d > 0; d >>= 1) lp += __shfl_down(lp, d);
        if (t == 0) loss_p[blockIdx.x] = lp;
    }
}

// ---------------------------------------------------------------------------
// Kernel 3 (R4): the ENTIRE tail fused into one cooperative kernel.
// 512 blocks x 256 threads, grid.sync() between dependency phases:
//   A: exact fp32 re-argmin for flagged points (patches idx/hist/loss)
//   B: hist scan -> cursor + cluster-size EMA/Laplace + loss reduce (blk 0)
//   C: counting-sort scatter
//   D: segmented dw reduction (reads zf)
//   E: z_q gather (overwrites zf region — all readers done) + finalize2
// Replaces 6 kernel launches (+gaps) with 1 launch + 4 grid syncs.
__global__ __launch_bounds__(256) void tail_kernel(
        float* zf, const float* __restrict__ emb, const float* __restrict__ esq,
        const int* __restrict__ flagcnt, const int* __restrict__ flaglist,
        const float* __restrict__ flagval, int* __restrict__ idx_i,
        float* __restrict__ idx_f, int* __restrict__ hist,
        float* loss_fix, int* __restrict__ cursor,
        const float* __restrict__ ema_cs, const float* __restrict__ loss_p,
        float* __restrict__ cs_out, float* __restrict__ loss_out,
        int* __restrict__ sorted, int* __restrict__ codes_s,
        float* dw, const float* __restrict__ ema_w,
        float* new_emb_out, float* __restrict__ new_ema_w_out) {
    cg::grid_group grid = cg::this_grid();
    __shared__ float zrow[256];
    __shared__ ull red[256];
    __shared__ int wsum[4];
    __shared__ float wr[4], wr2[4];
    __shared__ int sid[64];
    __shared__ int scode[65];
    const int t = threadIdx.x;
    const int bid = blockIdx.x;

    // ---- Phase A: exact fp32 re-argmin for flagged points --------------
    {
        const int total = flagcnt[0];
        for (int fi = bid; fi < total; fi += 512) {
            const int n = flaglist[fi];
            __syncthreads();
            zrow[t] = zf[(size_t)n * Dd + t];
            __syncthreads();
            ull best = ~0ull;
            #pragma unroll
            for (int kc = 0; kc < 4; ++kc) {
                const int k = t * 4 + kc;
                const float* ep = emb + (size_t)k * Dd;
                float dot = 0.0f;
                #pragma unroll 8
                for (int c4 = 0; c4 < 64; ++c4) {
                    const float4 e4 = *(const float4*)(ep + c4 * 4);
                    const float4 z4 = *(const float4*)&zrow[c4 * 4];
                    dot = fmaf(z4.x, e4.x, dot);
                    dot = fmaf(z4.y, e4.y, dot);
                    dot = fmaf(z4.z, e4.z, dot);
                    dot = fmaf(z4.w, e4.w, dot);
                }
                const float val = esq[k] - 2.0f * dot;
                const ull pk = ((ull)mono(__float_as_uint(val)) << 32) | (unsigned)k;
                if (pk < best) best = pk;
            }
            red[t] = best;
            __syncthreads();
            for (int s = 128; s > 0; s >>= 1) {
                if (t < s) { if (red[t + s] < red[t]) red[t] = red[t + s]; }
                __syncthreads();
            }
            if (t == 0) {
                const int knew = (int)(unsigned)(red[0] & 0xFFFFFFFFull);
                const float vnew = unmono((unsigned)(red[0] >> 32));
                const int kold = idx_i[n];
                if (knew != kold) {
                    idx_i[n] = knew;
                    idx_f[n] = (float)knew;
                    atomicSub(&hist[kold], 1);
                    atomicAdd(&hist[knew], 1);
                }
                atomicAdd(loss_fix, vnew - flagval[fi]);
            }
        }
    }
    __threadfence();
    grid.sync();

    // ---- Phase B: scan + EMA/Laplace + loss (block 0, 4 codes/thread) --
    if (bid == 0) {
        const int w = t >> 6, lane = t & 63;
        const int k0 = t * 4;
        const int h0 = hist[k0], h1 = hist[k0 + 1], h2 = hist[k0 + 2], h3 = hist[k0 + 3];
        const int s4 = h0 + h1 + h2 + h3;
        int x = s4;
        #pragma unroll
        for (int d = 1; d < 64; d <<= 1) {
            const int o = __shfl_up(x, d);
            if (lane >= d) x += o;
        }
        const float c0 = ema_cs[k0] * DECAY + (1.0f - DECAY) * (float)h0;
        const float c1 = ema_cs[k0 + 1] * DECAY + (1.0f - DECAY) * (float)h1;
        const float c2 = ema_cs[k0 + 2] * DECAY + (1.0f - DECAY) * (float)h2;
        const float c3 = ema_cs[k0 + 3] * DECAY + (1.0f - DECAY) * (float)h3;
        float r = c0 + c1 + c2 + c3;
        float r2 = loss_p[t] + loss_p[t + 256];
        #pragma unroll
        for (int d = 32; d > 0; d >>= 1) { r += __shfl_xor(r, d); r2 += __shfl_xor(r2, d); }
        if (lane == 63) wsum[w] = x;
        if (lane == 0) { wr[w] = r; wr2[w] = r2; }
        __syncthreads();
        int base = 0;
        #pragma unroll
        for (int ww = 0; ww < 4; ++ww) if (ww < w) base += wsum[ww];
        const float nsum = wr[0] + wr[1] + wr[2] + wr[3];
        const int e0 = base + x - s4;
        int4 cur4;
        cur4.x = e0;
        cur4.y = e0 + h0;
        cur4.z = e0 + h0 + h1;
        cur4.w = e0 + h0 + h1 + h2;
        *(int4*)(cursor + k0) = cur4;
        const float scale = nsum / (nsum + (float)Kk * EPSV);
        cs_out[k0]     = (c0 + EPSV) * scale;   // cs_out base is only 4B-aligned
        cs_out[k0 + 1] = (c1 + EPSV) * scale;
        cs_out[k0 + 2] = (c2 + EPSV) * scale;
        cs_out[k0 + 3] = (c3 + EPSV) * scale;
        if (t == 0)
            loss_out[0] = BETA * (wr2[0] + wr2[1] + wr2[2] + wr2[3] + loss_fix[0]) / (float)ZELEM;
    }
    __threadfence();
    grid.sync();

    // ---- Phase C: counting-sort scatter --------------------------------
    if (bid < 128) {
        const int n = bid * 256 + t;
        const int j = idx_i[n];
        const int pos = atomicAdd(&cursor[j], 1);
        sorted[pos] = n;
        codes_s[pos] = j;
    }
    __threadfence();
    grid.sync();

    // ---- Phase D: segmented dw reduction (reads zf) --------------------
    {
        const int p0 = bid * 64;
        if (t < 64) { sid[t] = sorted[p0 + t]; scode[t] = codes_s[p0 + t]; }
        if (t == 64) scode[64] = -1;
        __syncthreads();
        float acc = 0.0f;
        #pragma unroll 8
        for (int p = 0; p < 64; ++p) {
            acc += zf[(size_t)sid[p] * Dd + t];
            if (scode[p] != scode[p + 1]) {
                atomicAdd(&dw[(size_t)scode[p] * Dd + t], acc);
                acc = 0.0f;
            }
        }
    }
    __threadfence();
    grid.sync();

    // ---- Phase E: z_q gather (overwrites zf) + finalize2 ---------------
    #pragma unroll 4
    for (int it = 0; it < 16; ++it) {
        const int tid = (bid * 16 + it) * 256 + t;
        const int e0 = tid * 4;
        const int c = (e0 >> 10) & 255;
        const int b = e0 >> 18;
        const int n0 = b * 1024 + (e0 & 1023);
        const int4 j4 = *(const int4*)(idx_i + n0);
        float4 e;
        e.x = emb[(size_t)j4.x * Dd + c];
        e.y = emb[(size_t)j4.y * Dd + c];
        e.z = emb[(size_t)j4.z * Dd + c];
        e.w = emb[(size_t)j4.w * Dd + c];
        *(float4*)(zf + e0) = e;
    }
    #pragma unroll
    for (int it = 0; it < 2; ++it) {
        const int i = it * 131072 + bid * 256 + t;
        const float nw = ema_w[i] * DECAY + (1.0f - DECAY) * dw[i];
        const float cs = cs_out[i >> 8];
        new_ema_w_out[i] = nw;      // dw aliases new_emb_out: read-before-write
        new_emb_out[i]   = nw / cs; // same thread, same index — race-free
    }
}

// ---------------------------------------------------------------------------
extern "C" void kernel_launch(void* const* d_in, const int* in_sizes, int n_in,
                              void* d_out, int out_size, void* d_ws, size_t ws_size,
                              hipStream_t stream) {
    const float* z      = (const float*)d_in[0];
    const float* emb    = (const float*)d_in[1];
    const float* ema_cs = (const float*)d_in[2];
    const float* ema_w  = (const float*)d_in[3];

    float* out = (float*)d_out;
    float* zq_out        = out;                 // 8388608 (zf staging until gather)
    float* idx_out_f     = out + 8388608;       // 32768
    float* loss_out      = out + 8421376;       // 1
    float* new_emb_out   = out + 8421377;       // 262144 (dw staging)
    float* cs_out        = out + 8683521;       // 1024
    float* new_ema_w_out = out + 8684545;       // 262144

    int*   idx_i    = (int*)d_ws;                    // 32768
    int*   sorted   = idx_i + 32768;                 // 32768
    int*   codes_s  = sorted + 32768;                // 32768
    int*   offsets  = codes_s + 32768;               // 1024 (legacy slot, unused)
    int*   cursor   = offsets + 1024;                // 1024
    int*   hist     = cursor + 1024;                 // 1024
    int*   flagcnt  = hist + 1024;                   // 16
    float* loss_fix = (float*)(flagcnt + 16);        // 16
    int*   flaglist = (int*)(loss_fix + 16);         // 32768
    float* flagval  = (float*)(flaglist + 32768);    // 32768
    float* esq      = flagval + 32768;               // 1024
    float* loss_p   = esq + 1024;                    // 512
    unsigned short* ehg = (unsigned short*)(loss_p + 512);  // 262144 shorts
    unsigned short* elg = ehg + 262144;                     // 262144 shorts

    float* zf = zq_out;        // transposed z staged in zq output region
    float* dw = new_emb_out;   // dw staged in new_embedding output region

    prep_e_kernel<<<64, 256, 0, stream>>>(emb, ehg, elg, esq, hist, flagcnt,
                                          loss_fix, dw);
    dist_kernel<<<Nn / 64, 256, 0, stream>>>(z, ehg, elg, esq, zf, idx_i,
                                             idx_out_f, hist, flagcnt,
                                             flaglist, flagval, loss_p);
    void* kargs[] = {
        (void*)&zf, (void*)&emb, (void*)&esq, (void*)&flagcnt, (void*)&flaglist,
        (void*)&flagval, (void*)&idx_i, (void*)&idx_out_f, (void*)&hist,
        (void*)&loss_fix, (void*)&cursor, (void*)&ema_cs, (void*)&loss_p,
        (void*)&cs_out, (void*)&loss_out, (void*)&sorted, (void*)&codes_s,
        (void*)&dw, (void*)&ema_w, (void*)&new_emb_out, (void*)&new_ema_w_out
    };
    hipLaunchCooperativeKernel((void*)tail_kernel, dim3(512), dim3(256),
                               kargs, 0, stream);
}

// Round 5
// 245.283 us; speedup vs baseline: 2.5817x; 2.5817x over previous
//
#include <hip/hip_runtime.h>

typedef unsigned long long ull;
typedef __attribute__((ext_vector_type(8))) short bf16x8;
typedef __attribute__((ext_vector_type(4))) float f32x4;
typedef __attribute__((ext_vector_type(8))) unsigned short u16x8;

#define DECAY 0.99f
#define BETA 0.25f
#define EPSV 1e-5f
#define EPSGAP 0.0625f

// z: [32, 256, 32, 32] fp32 ; embedding: [1024, 256] ; N = 32*32*32 = 32768
#define Dd 256
#define Kk 1024
#define Nn 32768
#define ZELEM 8388608

__device__ __forceinline__ unsigned short f2bf(float f) {
    unsigned int x = __float_as_uint(f);
    x += 0x7FFFu + ((x >> 16) & 1u);          // RNE
    return (unsigned short)(x >> 16);
}
__device__ __forceinline__ float bf2f(unsigned short b) {
    return __uint_as_float(((unsigned int)b) << 16);
}
__device__ __forceinline__ unsigned mono(unsigned b) {
    return b ^ (((int)b >> 31) | 0x80000000u);   // monotone float->uint
}
__device__ __forceinline__ float unmono(unsigned m) {
    unsigned b = (m & 0x80000000u) ? (m ^ 0x80000000u) : ~m;
    return __uint_as_float(b);
}
__device__ __forceinline__ unsigned umin32(unsigned a, unsigned b) { return a < b ? a : b; }
__device__ __forceinline__ unsigned umax32(unsigned a, unsigned b) { return a > b ? a : b; }

// ---------------------------------------------------------------------------
// Kernel 1: pre-split embedding into MFMA-B-fragment order (hi/lo bf16),
// compute esq; zero hist / flagcnt / loss_fix / dw. 64 blocks.
__global__ __launch_bounds__(256) void prep_e_kernel(
        const float* __restrict__ emb, unsigned short* __restrict__ ehg,
        unsigned short* __restrict__ elg, float* __restrict__ esq,
        int* __restrict__ hist, int* __restrict__ flagcnt,
        float* __restrict__ loss_fix, float* __restrict__ dw) {
    const int nsub = blockIdx.x;
    const int t = threadIdx.x;
    if (t < 16) hist[nsub * 16 + t] = 0;
    if (nsub == 0 && t == 16) flagcnt[0] = 0;
    if (nsub == 0 && t == 17) loss_fix[0] = 0.0f;
    {
        float4* dwp = (float4*)dw;
        #pragma unroll
        for (int j = 0; j < 4; ++j)
            dwp[(size_t)(nsub * 256 + t) * 4 + j] = make_float4(0.f, 0.f, 0.f, 0.f);
    }
    #pragma unroll
    for (int it = 0; it < 2; ++it) {
        const int item = it * 256 + t;
        const int kc = item >> 6, lane = item & 63;
        const int quad = lane >> 4, nl = lane & 15;
        const float* ep = emb + (size_t)(nsub * 16 + nl) * Dd + kc * 32 + quad * 8;
        const float4 a = *(const float4*)ep;
        const float4 b4 = *(const float4*)(ep + 4);
        const float v[8] = {a.x, a.y, a.z, a.w, b4.x, b4.y, b4.z, b4.w};
        u16x8 hi, lo;
        #pragma unroll
        for (int j = 0; j < 8; ++j) {
            const unsigned short h = f2bf(v[j]);
            hi[j] = h;
            lo[j] = f2bf(v[j] - bf2f(h));
        }
        const size_t off = ((size_t)(nsub * 8 + kc) * 64 + lane) * 8;
        *(u16x8*)&ehg[off] = hi;
        *(u16x8*)&elg[off] = lo;
    }
    {
        const int nl = t >> 4, seg = t & 15;
        const float* ep = emb + (size_t)(nsub * 16 + nl) * Dd + seg * 16;
        float s = 0.0f;
        #pragma unroll
        for (int j = 0; j < 4; ++j) {
            const float4 v4 = *(const float4*)(ep + j * 4);
            s += v4.x * v4.x + v4.y * v4.y + v4.z * v4.z + v4.w * v4.w;
        }
        #pragma unroll
        for (int d = 1; d < 16; d <<= 1) s += __shfl_xor(s, d);
        if (seg == 0) esq[nsub * 16 + nl] = s;
    }
}

// ---------------------------------------------------------------------------
// Kernel 2: MFMA distance + top-2 argmin + hist + loss, PLUS (R5):
//  - z_q written directly in [B,C,HW] layout (emb rows staged via LDS,
//    aliasing the dead zh/zl region, padded [64][257] = bank-conflict-free)
//  - dw accumulated via atomicAdd from the LDS hi/lo reconstruction
// zf is GONE: no transpose output, no sort/dw_seg/gather kernels.
// R1: fused transpose->now removed; T5 setprio kept. R3 A-dbuf kept.
__global__ __launch_bounds__(256) void dist_kernel(
        const float* __restrict__ z, const unsigned short* __restrict__ ehg,
        const unsigned short* __restrict__ elg, const float* __restrict__ esq,
        const float* __restrict__ emb,
        float* __restrict__ zq, float* __restrict__ dw,
        int* __restrict__ idx_i, float* __restrict__ idx_f,
        int* __restrict__ hist, int* __restrict__ flagcnt,
        int* __restrict__ flaglist, float* __restrict__ flagval,
        float* __restrict__ loss_p) {
    __shared__ __align__(16) unsigned char smem[70656];
    __shared__ int kidx[64];
    unsigned short* zh = (unsigned short*)smem;            // 32KB  [0,32768)
    unsigned short* zl = (unsigned short*)(smem + 32768);  // 32KB  [32768,65536)
    ull* mb   = (ull*)(smem + 65536);                      // 4*64 ull (2KB)
    ull* ms   = (ull*)(smem + 67584);                      // 4*64 ull (2KB)
    float* zsqp = (float*)(smem + 69632);                  // 256 f32 (1KB)
    float* eldsf = (float*)smem;                           // [64][257] f32, aliases zh/zl/mb (dead by then)

    const int t = threadIdx.x, w = t >> 6, L = t & 63;
    const int quad = L >> 4, lr = L & 15;
    const int m0 = blockIdx.x * 64;
    const int b = m0 >> 10, hw0 = m0 & 1023;

    // ---- stage: wave w converts channels w*64..+63 for all 64 points
    {
        const int c0 = w * 64;
        const float* zp = z + (size_t)b * 262144 + hw0 + L;
        float s = 0.0f;
        #pragma unroll
        for (int cg = 0; cg < 8; ++cg) {
            float v[8];
            #pragma unroll
            for (int j = 0; j < 8; ++j)
                v[j] = zp[(size_t)(c0 + cg * 8 + j) * 1024];
            u16x8 hi, lo;
            #pragma unroll
            for (int j = 0; j < 8; ++j) {
                s = fmaf(v[j], v[j], s);
                const unsigned short h = f2bf(v[j]);
                hi[j] = h;
                lo[j] = f2bf(v[j] - bf2f(h));
            }
            const int chunk = ((c0 >> 3) + cg) ^ (L & 7);
            *(u16x8*)&zh[L * 256 + chunk * 8] = hi;
            *(u16x8*)&zl[L * 256 + chunk * 8] = lo;
        }
        zsqp[L * 4 + w] = s;
    }
    __syncthreads();

    const unsigned short* ehw = ehg + (size_t)(w * 1024 + L) * 8;
    const unsigned short* elw = elg + (size_t)(w * 1024 + L) * 8;

    unsigned bb[16], ss[16];
    #pragma unroll
    for (int i = 0; i < 16; ++i) { bb[i] = 0xFFFFFFFFu; ss[i] = 0xFFFFFFFFu; }

    bf16x8 Bh[2][2], Bl[2][2];
    #pragma unroll
    for (int ni = 0; ni < 2; ++ni) {
        Bh[0][ni] = *(const bf16x8*)(ehw + (size_t)ni * 4096);
        Bl[0][ni] = *(const bf16x8*)(elw + (size_t)ni * 4096);
    }
    bf16x8 Ah[2][4], Al[2][4];
    #pragma unroll
    for (int mi = 0; mi < 4; ++mi) {
        const int chunk = quad ^ (lr & 7);               // kc = 0
        const int o = (mi * 16 + lr) * 256 + chunk * 8;
        Ah[0][mi] = *(const bf16x8*)&zh[o];
        Al[0][mi] = *(const bf16x8*)&zl[o];
    }

    for (int nt = 0; nt < 8; ++nt) {
        f32x4 acc[4][2];
        #pragma unroll
        for (int mi = 0; mi < 4; ++mi)
            #pragma unroll
            for (int ni = 0; ni < 2; ++ni) acc[mi][ni] = (f32x4){0.f, 0.f, 0.f, 0.f};

        #pragma unroll
        for (int kc = 0; kc < 8; ++kc) {
            const int cur = kc & 1, nxt = cur ^ 1;
            const int nkc = (kc + 1) & 7;
            const int nnt = (kc == 7) ? ((nt + 1) & 7) : nt;
            #pragma unroll
            for (int ni = 0; ni < 2; ++ni) {
                const size_t o = (size_t)nnt * 32768 + (size_t)ni * 4096 + (size_t)nkc * 512;
                Bh[nxt][ni] = *(const bf16x8*)(ehw + o);
                Bl[nxt][ni] = *(const bf16x8*)(elw + o);
            }
            #pragma unroll
            for (int mi = 0; mi < 4; ++mi) {
                const int chunk = (nkc * 4 + quad) ^ (lr & 7);
                const int o = (mi * 16 + lr) * 256 + chunk * 8;
                Ah[nxt][mi] = *(const bf16x8*)&zh[o];
                Al[nxt][mi] = *(const bf16x8*)&zl[o];
            }
            __builtin_amdgcn_s_setprio(1);
            #pragma unroll
            for (int mi = 0; mi < 4; ++mi)
                #pragma unroll
                for (int ni = 0; ni < 2; ++ni) {
                    acc[mi][ni] = __builtin_amdgcn_mfma_f32_16x16x32_bf16(Ah[cur][mi], Bh[cur][ni], acc[mi][ni], 0, 0, 0);
                    acc[mi][ni] = __builtin_amdgcn_mfma_f32_16x16x32_bf16(Ah[cur][mi], Bl[cur][ni], acc[mi][ni], 0, 0, 0);
                    acc[mi][ni] = __builtin_amdgcn_mfma_f32_16x16x32_bf16(Al[cur][mi], Bh[cur][ni], acc[mi][ni], 0, 0, 0);
                }
            __builtin_amdgcn_s_setprio(0);
        }
        const int q0 = nt * 8 + w * 2;
        const float e0b = esq[q0 * 16 + lr] + 512.0f;
        const float e1b = esq[(q0 + 1) * 16 + lr] + 512.0f;
        #pragma unroll
        for (int mi = 0; mi < 4; ++mi)
            #pragma unroll
            for (int reg = 0; reg < 4; ++reg) {
                const int i = mi * 4 + reg;
                #pragma unroll
                for (int ni = 0; ni < 2; ++ni) {
                    const float val = fmaf(-2.0f, acc[mi][ni][reg], ni ? e1b : e0b);
                    const unsigned pk = (__float_as_uint(val) & 0xFFFFFFC0u) | (unsigned)(q0 + ni);
                    const unsigned mx = umax32(bb[i], pk);
                    bb[i] = umin32(bb[i], pk);
                    ss[i] = umin32(ss[i], mx);
                }
            }
    }

    #pragma unroll
    for (int mi = 0; mi < 4; ++mi)
        #pragma unroll
        for (int reg = 0; reg < 4; ++reg) {
            const int i = mi * 4 + reg;
            ull b2 = ((ull)(bb[i] & 0xFFFFFFC0u) << 14) | (ull)((bb[i] & 63u) * 16 + lr);
            ull s2 = ((ull)(ss[i] & 0xFFFFFFC0u) << 14) | (ull)((ss[i] & 63u) * 16 + lr);
            #pragma unroll
            for (int d = 1; d < 16; d <<= 1) {
                const ull ob = __shfl_xor(b2, d);
                const ull os = __shfl_xor(s2, d);
                const ull mx = ob < b2 ? b2 : ob;
                b2 = ob < b2 ? ob : b2;
                const ull ns = os < s2 ? os : s2;
                s2 = mx < ns ? mx : ns;
            }
            if (lr == 0) {
                const int row = mi * 16 + quad * 4 + reg;
                mb[w * 64 + row] = b2;
                ms[w * 64 + row] = s2;
            }
        }
    __syncthreads();

    if (t < 64) {
        ull b2 = mb[t], s2 = ms[t];
        #pragma unroll
        for (int ww = 1; ww < 4; ++ww) {
            const ull ob = mb[ww * 64 + t], os = ms[ww * 64 + t];
            const ull mx = ob < b2 ? b2 : ob;
            b2 = ob < b2 ? ob : b2;
            const ull ns = os < s2 ? os : s2;
            s2 = mx < ns ? mx : ns;
        }
        const int k = (int)(b2 & 16383ull);
        const float v1 = __uint_as_float((unsigned)(b2 >> 14)) - 512.0f;
        const float v2 = __uint_as_float((unsigned)(s2 >> 14)) - 512.0f;
        idx_i[m0 + t] = k;
        idx_f[m0 + t] = (float)k;
        kidx[t] = k;
        atomicAdd(&hist[k], 1);
        if (v2 - v1 < EPSGAP) {
            const int pos = atomicAdd(flagcnt, 1);
            flaglist[pos] = m0 + t;
            flagval[pos] = v1;
        }
        float lp = v1 + zsqp[t * 4] + zsqp[t * 4 + 1] + zsqp[t * 4 + 2] + zsqp[t * 4 + 3];
        #pragma unroll
        for (int d = 32; d > 0; d >>= 1) lp += __shfl_down(lp, d);
        if (t == 0) loss_p[blockIdx.x] = lp;
    }
    __syncthreads();

    // ---- Phase dw: thread t = channel c; hi+lo reconstruction -> atomicAdd
    {
        const int c = t;
        const int ch = c >> 3, cj = c & 7;
        #pragma unroll 4
        for (int p = 0; p < 64; ++p) {
            const int a = p * 256 + ((ch ^ (p & 7)) << 3) + cj;
            const float v = bf2f(zh[a]) + bf2f(zl[a]);
            atomicAdd(&dw[(size_t)kidx[p] * Dd + c], v);
        }
    }
    __syncthreads();

    // ---- Phase emb-load: the 64 code rows into eldsf[64][257] (zh/zl dead)
    for (int pr = w; pr < 64; pr += 4) {
        const float* er = emb + (size_t)kidx[pr] * Dd;
        #pragma unroll
        for (int g = 0; g < 4; ++g)
            eldsf[pr * 257 + g * 64 + L] = er[g * 64 + L];
    }
    __syncthreads();

    // ---- Phase z_q store: [B,C,HW] layout, coalesced float4 over hw
    {
        const int g = t & 15;          // hw quad group: hw = hw0 + g*4 .. +3
        const int cl = t >> 4;         // channel-within-pass
        float* zqb = zq + (size_t)b * 262144 + hw0 + g * 4;
        #pragma unroll
        for (int pass = 0; pass < 16; ++pass) {
            const int c = pass * 16 + cl;
            float4 v;
            v.x = eldsf[(g * 4 + 0) * 257 + c];
            v.y = eldsf[(g * 4 + 1) * 257 + c];
            v.z = eldsf[(g * 4 + 2) * 257 + c];
            v.w = eldsf[(g * 4 + 3) * 257 + c];
            *(float4*)(zqb + (size_t)c * 1024) = v;
        }
    }
}

// ---------------------------------------------------------------------------
// Kernel 3: exact fp32 re-argmin for flagged points; patches idx/hist/loss,
// AND (R5) patches dw (-zrow old, +zrow new) and the z_q row.
// zrow now read straight from z (strided; ~1e3 points -> few µs).
__global__ __launch_bounds__(256) void fixup_kernel(
        const float* __restrict__ z, const float* __restrict__ emb,
        const float* __restrict__ esq, const int* __restrict__ flagcnt,
        const int* __restrict__ flaglist, const float* __restrict__ flagval,
        int* __restrict__ idx_i, float* __restrict__ idx_f,
        int* __restrict__ hist, float* __restrict__ loss_fix,
        float* __restrict__ zq, float* __restrict__ dw) {
    __shared__ float zrow[256];
    __shared__ ull red[256];
    __shared__ int s_pair[2];
    const int t = threadIdx.x;
    const int total = flagcnt[0];
    for (int fi = blockIdx.x; fi < total; fi += 512) {
        const int n = flaglist[fi];
        const int b = n >> 10, hw = n & 1023;
        __syncthreads();
        zrow[t] = z[(size_t)b * 262144 + (size_t)t * 1024 + hw];
        __syncthreads();
        ull best = ~0ull;
        #pragma unroll
        for (int kc = 0; kc < 4; ++kc) {
            const int k = t * 4 + kc;
            const float* ep = emb + (size_t)k * Dd;
            float dot = 0.0f;
            #pragma unroll 8
            for (int c4 = 0; c4 < 64; ++c4) {
                const float4 e4 = *(const float4*)(ep + c4 * 4);
                const float4 z4 = *(const float4*)&zrow[c4 * 4];
                dot = fmaf(z4.x, e4.x, dot);
                dot = fmaf(z4.y, e4.y, dot);
                dot = fmaf(z4.z, e4.z, dot);
                dot = fmaf(z4.w, e4.w, dot);
            }
            const float val = esq[k] - 2.0f * dot;
            const ull pk = ((ull)mono(__float_as_uint(val)) << 32) | (unsigned)k;
            if (pk < best) best = pk;
        }
        red[t] = best;
        __syncthreads();
        for (int s = 128; s > 0; s >>= 1) {
            if (t < s) { if (red[t + s] < red[t]) red[t] = red[t + s]; }
            __syncthreads();
        }
        if (t == 0) {
            const int knew = (int)(unsigned)(red[0] & 0xFFFFFFFFull);
            const float vnew = unmono((unsigned)(red[0] >> 32));
            const int kold = idx_i[n];
            s_pair[0] = kold;
            s_pair[1] = knew;
            if (knew != kold) {
                idx_i[n] = knew;
                idx_f[n] = (float)knew;
                atomicSub(&hist[kold], 1);
                atomicAdd(&hist[knew], 1);
            }
            atomicAdd(loss_fix, vnew - flagval[fi]);
        }
        __syncthreads();
        const int kold = s_pair[0], knew = s_pair[1];
        if (knew != kold) {
            const float zv = zrow[t];
            atomicAdd(&dw[(size_t)kold * Dd + t], -zv);
            atomicAdd(&dw[(size_t)knew * Dd + t], zv);
            zq[(size_t)b * 262144 + (size_t)t * 1024 + hw] = emb[(size_t)knew * Dd + t];
        }
    }
}

// ---------------------------------------------------------------------------
// Kernel 4: cluster-size EMA + Laplace smoothing + loss reduce. 1 block,
// wave-shuffle (no cursor/offsets needed anymore — counting sort is gone).
__global__ void scan_fin1_kernel(const int* __restrict__ hist,
                                 const float* __restrict__ ema_cs,
                                 const float* __restrict__ loss_p,
                                 const float* __restrict__ loss_fix,
                                 float* __restrict__ cs_out,
                                 float* __restrict__ loss_out) {
    __shared__ float wred[16], wred2[16];
    const int t = threadIdx.x;            // 1024 threads = 16 waves
    const int w = t >> 6, lane = t & 63;
    const int v = hist[t];
    const float csr = ema_cs[t] * DECAY + (1.0f - DECAY) * (float)v;
    float r = csr;
    float r2 = (t < 512) ? loss_p[t] : 0.0f;
    #pragma unroll
    for (int d = 32; d > 0; d >>= 1) { r += __shfl_xor(r, d); r2 += __shfl_xor(r2, d); }
    if (lane == 0) { wred[w] = r; wred2[w] = r2; }
    __syncthreads();
    if (t < 16) {
        float rr = wred[t], rr2 = wred2[t];
        #pragma unroll
        for (int d = 1; d < 16; d <<= 1) { rr += __shfl_xor(rr, d); rr2 += __shfl_xor(rr2, d); }
        if (t == 0) { wred[0] = rr; wred2[0] = rr2; }
    }
    __syncthreads();
    const float nsum = wred[0];
    const float cs = (csr + EPSV) / (nsum + (float)Kk * EPSV) * nsum;
    cs_out[t] = cs;
    if (t == 0) loss_out[0] = BETA * (wred2[0] + loss_fix[0]) / (float)ZELEM;
}

// ---------------------------------------------------------------------------
// Kernel 5: new_ema_w = EMA(ema_w, dw); new_emb = new_ema_w / cs.
// dw aliases new_emb_out; each thread reads dw[i] then overwrites same i.
__global__ __launch_bounds__(256) void finalize2_kernel(
        const float* __restrict__ ema_w, const float* __restrict__ dw,
        const float* __restrict__ cs_out,
        float* __restrict__ new_emb_out, float* __restrict__ new_ema_w_out) {
    const int i = blockIdx.x * 256 + threadIdx.x;
    const float nw = ema_w[i] * DECAY + (1.0f - DECAY) * dw[i];
    const float cs = cs_out[i >> 8];
    new_ema_w_out[i] = nw;
    new_emb_out[i]   = nw / cs;
}

// ---------------------------------------------------------------------------
extern "C" void kernel_launch(void* const* d_in, const int* in_sizes, int n_in,
                              void* d_out, int out_size, void* d_ws, size_t ws_size,
                              hipStream_t stream) {
    const float* z      = (const float*)d_in[0];
    const float* emb    = (const float*)d_in[1];
    const float* ema_cs = (const float*)d_in[2];
    const float* ema_w  = (const float*)d_in[3];

    float* out = (float*)d_out;
    float* zq_out        = out;                 // 8388608 (z_q written directly by dist)
    float* idx_out_f     = out + 8388608;       // 32768
    float* loss_out      = out + 8421376;       // 1
    float* new_emb_out   = out + 8421377;       // 262144 (dw staging)
    float* cs_out        = out + 8683521;       // 1024
    float* new_ema_w_out = out + 8684545;       // 262144

    int*   idx_i    = (int*)d_ws;                    // 32768
    int*   flagcnt  = idx_i + 32768;                 // 16
    float* loss_fix = (float*)(flagcnt + 16);        // 16
    int*   flaglist = (int*)(loss_fix + 16);         // 32768
    float* flagval  = (float*)(flaglist + 32768);    // 32768
    int*   hist     = (int*)(flagval + 32768);       // 1024
    float* esq      = (float*)(hist + 1024);         // 1024
    float* loss_p   = esq + 1024;                    // 512
    unsigned short* ehg = (unsigned short*)(loss_p + 512);  // 262144 shorts
    unsigned short* elg = ehg + 262144;                     // 262144 shorts

    float* dw = new_emb_out;   // dw staged in new_embedding output region

    prep_e_kernel<<<64, 256, 0, stream>>>(emb, ehg, elg, esq, hist, flagcnt,
                                          loss_fix, dw);
    dist_kernel<<<Nn / 64, 256, 0, stream>>>(z, ehg, elg, esq, emb, zq_out, dw,
                                             idx_i, idx_out_f, hist, flagcnt,
                                             flaglist, flagval, loss_p);
    fixup_kernel<<<512, 256, 0, stream>>>(z, emb, esq, flagcnt, flaglist,
                                          flagval, idx_i, idx_out_f, hist,
                                          loss_fix, zq_out, dw);
    scan_fin1_kernel<<<1, 1024, 0, stream>>>(hist, ema_cs, loss_p, loss_fix,
                                             cs_out, loss_out);
    finalize2_kernel<<<Kk * Dd / 256, 256, 0, stream>>>(ema_w, dw, cs_out,
                                                        new_emb_out, new_ema_w_out);
}

// Round 6
// 237.023 us; speedup vs baseline: 2.6716x; 1.0348x over previous
//
#include <hip/hip_runtime.h>

typedef unsigned long long ull;
typedef __attribute__((ext_vector_type(8))) short bf16x8;
typedef __attribute__((ext_vector_type(4))) float f32x4;
typedef __attribute__((ext_vector_type(8))) unsigned short u16x8;

#define DECAY 0.99f
#define BETA 0.25f
#define EPSV 1e-5f
#define EPSGAP 0.0625f

// z: [32, 256, 32, 32] fp32 ; embedding: [1024, 256] ; N = 32*32*32 = 32768
#define Dd 256
#define Kk 1024
#define Nn 32768
#define ZELEM 8388608

__device__ __forceinline__ unsigned short f2bf(float f) {
    unsigned int x = __float_as_uint(f);
    x += 0x7FFFu + ((x >> 16) & 1u);          // RNE
    return (unsigned short)(x >> 16);
}
__device__ __forceinline__ float bf2f(unsigned short b) {
    return __uint_as_float(((unsigned int)b) << 16);
}
__device__ __forceinline__ unsigned mono(unsigned b) {
    return b ^ (((int)b >> 31) | 0x80000000u);   // monotone float->uint
}
__device__ __forceinline__ float unmono(unsigned m) {
    unsigned b = (m & 0x80000000u) ? (m ^ 0x80000000u) : ~m;
    return __uint_as_float(b);
}
__device__ __forceinline__ unsigned umin32(unsigned a, unsigned b) { return a < b ? a : b; }
__device__ __forceinline__ unsigned umax32(unsigned a, unsigned b) { return a > b ? a : b; }

// ---------------------------------------------------------------------------
// Kernel 1: pre-split embedding into MFMA-B-fragment order (hi/lo bf16),
// compute esq; zero hist / flagcnt / loss_fix. 64 blocks.
// (dw replicas zeroed by hipMemsetAsync in kernel_launch.)
__global__ __launch_bounds__(256) void prep_e_kernel(
        const float* __restrict__ emb, unsigned short* __restrict__ ehg,
        unsigned short* __restrict__ elg, float* __restrict__ esq,
        int* __restrict__ hist, int* __restrict__ flagcnt,
        float* __restrict__ loss_fix) {
    const int nsub = blockIdx.x;
    const int t = threadIdx.x;
    if (t < 16) hist[nsub * 16 + t] = 0;
    if (nsub == 0 && t == 16) flagcnt[0] = 0;
    if (nsub == 0 && t == 17) loss_fix[0] = 0.0f;
    #pragma unroll
    for (int it = 0; it < 2; ++it) {
        const int item = it * 256 + t;
        const int kc = item >> 6, lane = item & 63;
        const int quad = lane >> 4, nl = lane & 15;
        const float* ep = emb + (size_t)(nsub * 16 + nl) * Dd + kc * 32 + quad * 8;
        const float4 a = *(const float4*)ep;
        const float4 b4 = *(const float4*)(ep + 4);
        const float v[8] = {a.x, a.y, a.z, a.w, b4.x, b4.y, b4.z, b4.w};
        u16x8 hi, lo;
        #pragma unroll
        for (int j = 0; j < 8; ++j) {
            const unsigned short h = f2bf(v[j]);
            hi[j] = h;
            lo[j] = f2bf(v[j] - bf2f(h));
        }
        const size_t off = ((size_t)(nsub * 8 + kc) * 64 + lane) * 8;
        *(u16x8*)&ehg[off] = hi;
        *(u16x8*)&elg[off] = lo;
    }
    {
        const int nl = t >> 4, seg = t & 15;
        const float* ep = emb + (size_t)(nsub * 16 + nl) * Dd + seg * 16;
        float s = 0.0f;
        #pragma unroll
        for (int j = 0; j < 4; ++j) {
            const float4 v4 = *(const float4*)(ep + j * 4);
            s += v4.x * v4.x + v4.y * v4.y + v4.z * v4.z + v4.w * v4.w;
        }
        #pragma unroll
        for (int d = 1; d < 16; d <<= 1) s += __shfl_xor(s, d);
        if (seg == 0) esq[nsub * 16 + nl] = s;
    }
}

// ---------------------------------------------------------------------------
// Kernel 2: MFMA distance + top-2 argmin + hist + loss + z_q store + dw.
// R5 lesson: dw atomics on the block critical path (vmcnt(0) drain before
// the next __syncthreads) + hot-line contention cost ~80 µs. R6:
//  - dw phase moved to the VERY END (no trailing barrier -> completion
//    off the critical path), fed by re-reading z (L2/L3-resident).
//  - dw replicated x8 by blockIdx&mask -> 8x less same-line contention.
__global__ __launch_bounds__(256) void dist_kernel(
        const float* __restrict__ z, const unsigned short* __restrict__ ehg,
        const unsigned short* __restrict__ elg, const float* __restrict__ esq,
        const float* __restrict__ emb,
        float* __restrict__ zq, float* __restrict__ dwr, int repmask,
        int* __restrict__ idx_i, float* __restrict__ idx_f,
        int* __restrict__ hist, int* __restrict__ flagcnt,
        int* __restrict__ flaglist, float* __restrict__ flagval,
        float* __restrict__ loss_p) {
    __shared__ __align__(16) unsigned char smem[70656];
    __shared__ int kidx[64];
    unsigned short* zh = (unsigned short*)smem;            // 32KB  [0,32768)
    unsigned short* zl = (unsigned short*)(smem + 32768);  // 32KB  [32768,65536)
    ull* mb   = (ull*)(smem + 65536);                      // 4*64 ull (2KB)
    ull* ms   = (ull*)(smem + 67584);                      // 4*64 ull (2KB)
    float* zsqp = (float*)(smem + 69632);                  // 256 f32 (1KB)
    float* eldsf = (float*)smem;                           // [64][257] f32 (65792B); aliases zh/zl/mb/ms, all dead when written

    const int t = threadIdx.x, w = t >> 6, L = t & 63;
    const int quad = L >> 4, lr = L & 15;
    const int m0 = blockIdx.x * 64;
    const int b = m0 >> 10, hw0 = m0 & 1023;

    // ---- stage: wave w converts channels w*64..+63 for all 64 points
    {
        const int c0 = w * 64;
        const float* zp = z + (size_t)b * 262144 + hw0 + L;
        float s = 0.0f;
        #pragma unroll
        for (int cg = 0; cg < 8; ++cg) {
            float v[8];
            #pragma unroll
            for (int j = 0; j < 8; ++j)
                v[j] = zp[(size_t)(c0 + cg * 8 + j) * 1024];
            u16x8 hi, lo;
            #pragma unroll
            for (int j = 0; j < 8; ++j) {
                s = fmaf(v[j], v[j], s);
                const unsigned short h = f2bf(v[j]);
                hi[j] = h;
                lo[j] = f2bf(v[j] - bf2f(h));
            }
            const int chunk = ((c0 >> 3) + cg) ^ (L & 7);
            *(u16x8*)&zh[L * 256 + chunk * 8] = hi;
            *(u16x8*)&zl[L * 256 + chunk * 8] = lo;
        }
        zsqp[L * 4 + w] = s;
    }
    __syncthreads();

    const unsigned short* ehw = ehg + (size_t)(w * 1024 + L) * 8;
    const unsigned short* elw = elg + (size_t)(w * 1024 + L) * 8;

    unsigned bb[16], ss[16];
    #pragma unroll
    for (int i = 0; i < 16; ++i) { bb[i] = 0xFFFFFFFFu; ss[i] = 0xFFFFFFFFu; }

    bf16x8 Bh[2][2], Bl[2][2];
    #pragma unroll
    for (int ni = 0; ni < 2; ++ni) {
        Bh[0][ni] = *(const bf16x8*)(ehw + (size_t)ni * 4096);
        Bl[0][ni] = *(const bf16x8*)(elw + (size_t)ni * 4096);
    }
    bf16x8 Ah[2][4], Al[2][4];
    #pragma unroll
    for (int mi = 0; mi < 4; ++mi) {
        const int chunk = quad ^ (lr & 7);               // kc = 0
        const int o = (mi * 16 + lr) * 256 + chunk * 8;
        Ah[0][mi] = *(const bf16x8*)&zh[o];
        Al[0][mi] = *(const bf16x8*)&zl[o];
    }

    for (int nt = 0; nt < 8; ++nt) {
        f32x4 acc[4][2];
        #pragma unroll
        for (int mi = 0; mi < 4; ++mi)
            #pragma unroll
            for (int ni = 0; ni < 2; ++ni) acc[mi][ni] = (f32x4){0.f, 0.f, 0.f, 0.f};

        #pragma unroll
        for (int kc = 0; kc < 8; ++kc) {
            const int cur = kc & 1, nxt = cur ^ 1;
            const int nkc = (kc + 1) & 7;
            const int nnt = (kc == 7) ? ((nt + 1) & 7) : nt;
            #pragma unroll
            for (int ni = 0; ni < 2; ++ni) {
                const size_t o = (size_t)nnt * 32768 + (size_t)ni * 4096 + (size_t)nkc * 512;
                Bh[nxt][ni] = *(const bf16x8*)(ehw + o);
                Bl[nxt][ni] = *(const bf16x8*)(elw + o);
            }
            #pragma unroll
            for (int mi = 0; mi < 4; ++mi) {
                const int chunk = (nkc * 4 + quad) ^ (lr & 7);
                const int o = (mi * 16 + lr) * 256 + chunk * 8;
                Ah[nxt][mi] = *(const bf16x8*)&zh[o];
                Al[nxt][mi] = *(const bf16x8*)&zl[o];
            }
            __builtin_amdgcn_s_setprio(1);
            #pragma unroll
            for (int mi = 0; mi < 4; ++mi)
                #pragma unroll
                for (int ni = 0; ni < 2; ++ni) {
                    acc[mi][ni] = __builtin_amdgcn_mfma_f32_16x16x32_bf16(Ah[cur][mi], Bh[cur][ni], acc[mi][ni], 0, 0, 0);
                    acc[mi][ni] = __builtin_amdgcn_mfma_f32_16x16x32_bf16(Ah[cur][mi], Bl[cur][ni], acc[mi][ni], 0, 0, 0);
                    acc[mi][ni] = __builtin_amdgcn_mfma_f32_16x16x32_bf16(Al[cur][mi], Bh[cur][ni], acc[mi][ni], 0, 0, 0);
                }
            __builtin_amdgcn_s_setprio(0);
        }
        const int q0 = nt * 8 + w * 2;
        const float e0b = esq[q0 * 16 + lr] + 512.0f;
        const float e1b = esq[(q0 + 1) * 16 + lr] + 512.0f;
        #pragma unroll
        for (int mi = 0; mi < 4; ++mi)
            #pragma unroll
            for (int reg = 0; reg < 4; ++reg) {
                const int i = mi * 4 + reg;
                #pragma unroll
                for (int ni = 0; ni < 2; ++ni) {
                    const float val = fmaf(-2.0f, acc[mi][ni][reg], ni ? e1b : e0b);
                    const unsigned pk = (__float_as_uint(val) & 0xFFFFFFC0u) | (unsigned)(q0 + ni);
                    const unsigned mx = umax32(bb[i], pk);
                    bb[i] = umin32(bb[i], pk);
                    ss[i] = umin32(ss[i], mx);
                }
            }
    }

    #pragma unroll
    for (int mi = 0; mi < 4; ++mi)
        #pragma unroll
        for (int reg = 0; reg < 4; ++reg) {
            const int i = mi * 4 + reg;
            ull b2 = ((ull)(bb[i] & 0xFFFFFFC0u) << 14) | (ull)((bb[i] & 63u) * 16 + lr);
            ull s2 = ((ull)(ss[i] & 0xFFFFFFC0u) << 14) | (ull)((ss[i] & 63u) * 16 + lr);
            #pragma unroll
            for (int d = 1; d < 16; d <<= 1) {
                const ull ob = __shfl_xor(b2, d);
                const ull os = __shfl_xor(s2, d);
                const ull mx = ob < b2 ? b2 : ob;
                b2 = ob < b2 ? ob : b2;
                const ull ns = os < s2 ? os : s2;
                s2 = mx < ns ? mx : ns;
            }
            if (lr == 0) {
                const int row = mi * 16 + quad * 4 + reg;
                mb[w * 64 + row] = b2;
                ms[w * 64 + row] = s2;
            }
        }
    __syncthreads();

    if (t < 64) {
        ull b2 = mb[t], s2 = ms[t];
        #pragma unroll
        for (int ww = 1; ww < 4; ++ww) {
            const ull ob = mb[ww * 64 + t], os = ms[ww * 64 + t];
            const ull mx = ob < b2 ? b2 : ob;
            b2 = ob < b2 ? ob : b2;
            const ull ns = os < s2 ? os : s2;
            s2 = mx < ns ? mx : ns;
        }
        const int k = (int)(b2 & 16383ull);
        const float v1 = __uint_as_float((unsigned)(b2 >> 14)) - 512.0f;
        const float v2 = __uint_as_float((unsigned)(s2 >> 14)) - 512.0f;
        idx_i[m0 + t] = k;
        idx_f[m0 + t] = (float)k;
        kidx[t] = k;
        atomicAdd(&hist[k], 1);
        if (v2 - v1 < EPSGAP) {
            const int pos = atomicAdd(flagcnt, 1);
            flaglist[pos] = m0 + t;
            flagval[pos] = v1;
        }
        float lp = v1 + zsqp[t * 4] + zsqp[t * 4 + 1] + zsqp[t * 4 + 2] + zsqp[t * 4 + 3];
        #pragma unroll
        for (int d = 32; d > 0; d >>= 1) lp += __shfl_down(lp, d);
        if (t == 0) loss_p[blockIdx.x] = lp;
    }
    __syncthreads();

    // ---- Phase emb-load: the 64 code rows into eldsf[64][257] (zh/zl/mb dead)
    for (int pr = w; pr < 64; pr += 4) {
        const float* er = emb + (size_t)kidx[pr] * Dd;
        #pragma unroll
        for (int g = 0; g < 4; ++g)
            eldsf[pr * 257 + g * 64 + L] = er[g * 64 + L];
    }
    __syncthreads();

    // ---- Phase z_q store: [B,C,HW] layout, coalesced float4 over hw
    {
        const int g = t & 15;          // hw quad group: hw = hw0 + g*4 .. +3
        const int cl = t >> 4;         // channel-within-pass
        float* zqb = zq + (size_t)b * 262144 + hw0 + g * 4;
        #pragma unroll
        for (int pass = 0; pass < 16; ++pass) {
            const int c = pass * 16 + cl;
            float4 v;
            v.x = eldsf[(g * 4 + 0) * 257 + c];
            v.y = eldsf[(g * 4 + 1) * 257 + c];
            v.z = eldsf[(g * 4 + 2) * 257 + c];
            v.w = eldsf[(g * 4 + 3) * 257 + c];
            *(float4*)(zqb + (size_t)c * 1024) = v;
        }
    }

    // ---- Phase dw (LAST, no trailing barrier): exact z re-read (L2/L3
    // resident, 64KB/block) + replicated atomics. Completion drains at
    // wave retire, overlapping other blocks' work.
    {
        const int c = t;
        const float* zcol = z + (size_t)b * 262144 + (size_t)c * 1024 + hw0;
        float* dwb = dwr + (size_t)(blockIdx.x & repmask) * (Kk * Dd);
        #pragma unroll 4
        for (int p = 0; p < 64; ++p) {
            atomicAdd(&dwb[(size_t)kidx[p] * Dd + c], zcol[p]);
        }
    }
}

// ---------------------------------------------------------------------------
// Kernel 3: exact fp32 re-argmin for flagged points; patches idx/hist/loss,
// dw (replica 0) and the z_q row.
__global__ __launch_bounds__(256) void fixup_kernel(
        const float* __restrict__ z, const float* __restrict__ emb,
        const float* __restrict__ esq, const int* __restrict__ flagcnt,
        const int* __restrict__ flaglist, const float* __restrict__ flagval,
        int* __restrict__ idx_i, float* __restrict__ idx_f,
        int* __restrict__ hist, float* __restrict__ loss_fix,
        float* __restrict__ zq, float* __restrict__ dw) {
    __shared__ float zrow[256];
    __shared__ ull red[256];
    __shared__ int s_pair[2];
    const int t = threadIdx.x;
    const int total = flagcnt[0];
    for (int fi = blockIdx.x; fi < total; fi += 512) {
        const int n = flaglist[fi];
        const int b = n >> 10, hw = n & 1023;
        __syncthreads();
        zrow[t] = z[(size_t)b * 262144 + (size_t)t * 1024 + hw];
        __syncthreads();
        ull best = ~0ull;
        #pragma unroll
        for (int kc = 0; kc < 4; ++kc) {
            const int k = t * 4 + kc;
            const float* ep = emb + (size_t)k * Dd;
            float dot = 0.0f;
            #pragma unroll 8
            for (int c4 = 0; c4 < 64; ++c4) {
                const float4 e4 = *(const float4*)(ep + c4 * 4);
                const float4 z4 = *(const float4*)&zrow[c4 * 4];
                dot = fmaf(z4.x, e4.x, dot);
                dot = fmaf(z4.y, e4.y, dot);
                dot = fmaf(z4.z, e4.z, dot);
                dot = fmaf(z4.w, e4.w, dot);
            }
            const float val = esq[k] - 2.0f * dot;
            const ull pk = ((ull)mono(__float_as_uint(val)) << 32) | (unsigned)k;
            if (pk < best) best = pk;
        }
        red[t] = best;
        __syncthreads();
        for (int s = 128; s > 0; s >>= 1) {
            if (t < s) { if (red[t + s] < red[t]) red[t] = red[t + s]; }
            __syncthreads();
        }
        if (t == 0) {
            const int knew = (int)(unsigned)(red[0] & 0xFFFFFFFFull);
            const float vnew = unmono((unsigned)(red[0] >> 32));
            const int kold = idx_i[n];
            s_pair[0] = kold;
            s_pair[1] = knew;
            if (knew != kold) {
                idx_i[n] = knew;
                idx_f[n] = (float)knew;
                atomicSub(&hist[kold], 1);
                atomicAdd(&hist[knew], 1);
            }
            atomicAdd(loss_fix, vnew - flagval[fi]);
        }
        __syncthreads();
        const int kold = s_pair[0], knew = s_pair[1];
        if (knew != kold) {
            const float zv = zrow[t];
            atomicAdd(&dw[(size_t)kold * Dd + t], -zv);
            atomicAdd(&dw[(size_t)knew * Dd + t], zv);
            zq[(size_t)b * 262144 + (size_t)t * 1024 + hw] = emb[(size_t)knew * Dd + t];
        }
    }
}

// ---------------------------------------------------------------------------
// Kernel 4: cluster-size EMA + Laplace smoothing + loss reduce. 1 block.
__global__ void scan_fin1_kernel(const int* __restrict__ hist,
                                 const float* __restrict__ ema_cs,
                                 const float* __restrict__ loss_p,
                                 const float* __restrict__ loss_fix,
                                 float* __restrict__ cs_out,
                                 float* __restrict__ loss_out) {
    __shared__ float wred[16], wred2[16];
    const int t = threadIdx.x;            // 1024 threads = 16 waves
    const int w = t >> 6, lane = t & 63;
    const int v = hist[t];
    const float csr = ema_cs[t] * DECAY + (1.0f - DECAY) * (float)v;
    float r = csr;
    float r2 = (t < 512) ? loss_p[t] : 0.0f;
    #pragma unroll
    for (int d = 32; d > 0; d >>= 1) { r += __shfl_xor(r, d); r2 += __shfl_xor(r2, d); }
    if (lane == 0) { wred[w] = r; wred2[w] = r2; }
    __syncthreads();
    if (t < 16) {
        float rr = wred[t], rr2 = wred2[t];
        #pragma unroll
        for (int d = 1; d < 16; d <<= 1) { rr += __shfl_xor(rr, d); rr2 += __shfl_xor(rr2, d); }
        if (t == 0) { wred[0] = rr; wred2[0] = rr2; }
    }
    __syncthreads();
    const float nsum = wred[0];
    const float cs = (csr + EPSV) / (nsum + (float)Kk * EPSV) * nsum;
    cs_out[t] = cs;
    if (t == 0) loss_out[0] = BETA * (wred2[0] + loss_fix[0]) / (float)ZELEM;
}

// ---------------------------------------------------------------------------
// Kernel 5: sum dw replicas; new_ema_w = EMA(ema_w, dw); new_emb = nw / cs.
__global__ __launch_bounds__(256) void finalize2_kernel(
        const float* __restrict__ ema_w, const float* __restrict__ dwr,
        int nrep, const float* __restrict__ cs_out,
        float* __restrict__ new_emb_out, float* __restrict__ new_ema_w_out) {
    const int i = blockIdx.x * 256 + threadIdx.x;
    float s = 0.0f;
    for (int r = 0; r < nrep; ++r) s += dwr[(size_t)r * (Kk * Dd) + i];
    const float nw = ema_w[i] * DECAY + (1.0f - DECAY) * s;
    const float cs = cs_out[i >> 8];
    new_ema_w_out[i] = nw;
    new_emb_out[i]   = nw / cs;
}

// ---------------------------------------------------------------------------
extern "C" void kernel_launch(void* const* d_in, const int* in_sizes, int n_in,
                              void* d_out, int out_size, void* d_ws, size_t ws_size,
                              hipStream_t stream) {
    const float* z      = (const float*)d_in[0];
    const float* emb    = (const float*)d_in[1];
    const float* ema_cs = (const float*)d_in[2];
    const float* ema_w  = (const float*)d_in[3];

    float* out = (float*)d_out;
    float* zq_out        = out;                 // 8388608 (z_q written directly by dist)
    float* idx_out_f     = out + 8388608;       // 32768
    float* loss_out      = out + 8421376;       // 1
    float* new_emb_out   = out + 8421377;       // 262144
    float* cs_out        = out + 8683521;       // 1024
    float* new_ema_w_out = out + 8684545;       // 262144

    int*   idx_i    = (int*)d_ws;                    // 32768
    int*   flagcnt  = idx_i + 32768;                 // 16
    float* loss_fix = (float*)(flagcnt + 16);        // 16
    int*   flaglist = (int*)(loss_fix + 16);         // 32768
    float* flagval  = (float*)(flaglist + 32768);    // 32768
    int*   hist     = (int*)(flagval + 32768);       // 1024
    float* esq      = (float*)(hist + 1024);         // 1024
    float* loss_p   = esq + 1024;                    // 512
    unsigned short* ehg = (unsigned short*)(loss_p + 512);  // 262144 shorts
    unsigned short* elg = ehg + 262144;                     // 262144 shorts
    // dw replicas: after elg, 16B-aligned
    size_t dwr_off = ((size_t)((char*)(elg + 262144) - (char*)d_ws) + 255) & ~(size_t)255;
    float* dwr = (float*)((char*)d_ws + dwr_off);
    const size_t repbytes = (size_t)Kk * Dd * 4;     // 1MB per replica
    size_t rem = (ws_size > dwr_off) ? ws_size - dwr_off : 0;
    int nrep = 1;
    while (nrep < 8 && (size_t)(nrep * 2) * repbytes <= rem) nrep <<= 1;

    hipMemsetAsync(dwr, 0, (size_t)nrep * repbytes, stream);
    prep_e_kernel<<<64, 256, 0, stream>>>(emb, ehg, elg, esq, hist, flagcnt,
                                          loss_fix);
    dist_kernel<<<Nn / 64, 256, 0, stream>>>(z, ehg, elg, esq, emb, zq_out,
                                             dwr, nrep - 1, idx_i, idx_out_f,
                                             hist, flagcnt, flaglist, flagval,
                                             loss_p);
    fixup_kernel<<<512, 256, 0, stream>>>(z, emb, esq, flagcnt, flaglist,
                                          flagval, idx_i, idx_out_f, hist,
                                          loss_fix, zq_out, dwr);
    scan_fin1_kernel<<<1, 1024, 0, stream>>>(hist, ema_cs, loss_p, loss_fix,
                                             cs_out, loss_out);
    finalize2_kernel<<<Kk * Dd / 256, 256, 0, stream>>>(ema_w, dwr, nrep,
                                                        cs_out, new_emb_out,
                                                        new_ema_w_out);
}

// Round 8
// 231.632 us; speedup vs baseline: 2.7338x; 1.0233x over previous
//
#include <hip/hip_runtime.h>

typedef unsigned long long ull;
typedef __attribute__((ext_vector_type(8))) short bf16x8;
typedef __attribute__((ext_vector_type(4))) float f32x4;
typedef __attribute__((ext_vector_type(8))) unsigned short u16x8;

#define DECAY 0.99f
#define BETA 0.25f
#define EPSV 1e-5f
#define EPSGAP 0.0625f

// z: [32, 256, 32, 32] fp32 ; embedding: [1024, 256] ; N = 32*32*32 = 32768
#define Dd 256
#define Kk 1024
#define Nn 32768
#define ZELEM 8388608

__device__ __forceinline__ unsigned short f2bf(float f) {
    unsigned int x = __float_as_uint(f);
    x += 0x7FFFu + ((x >> 16) & 1u);          // RNE
    return (unsigned short)(x >> 16);
}
__device__ __forceinline__ float bf2f(unsigned short b) {
    return __uint_as_float(((unsigned int)b) << 16);
}
__device__ __forceinline__ unsigned mono(unsigned b) {
    return b ^ (((int)b >> 31) | 0x80000000u);   // monotone float->uint
}
__device__ __forceinline__ float unmono(unsigned m) {
    unsigned b = (m & 0x80000000u) ? (m ^ 0x80000000u) : ~m;
    return __uint_as_float(b);
}
__device__ __forceinline__ unsigned umin32(unsigned a, unsigned b) { return a < b ? a : b; }
__device__ __forceinline__ unsigned umax32(unsigned a, unsigned b) { return a > b ? a : b; }

// ---------------------------------------------------------------------------
// Kernel 1 (R7, resubmitted R8 — R7 bench was an infra failure, no defect
// found on audit): grid 512.
//  blocks 0..63 : emb hi/lo split + esq + zero hist/flagcnt/loss_fix
//  block 64     : reduce sum(ema_cs) -> nsum = 0.99*sum + 0.01*32768
//                 (valid because sum(hist)=32768 invariant, even after fixup)
//  ALL blocks   : zero their slice of the dw replicas (replaces hipMemsetAsync)
__global__ __launch_bounds__(256) void prep_e_kernel(
        const float* __restrict__ emb, unsigned short* __restrict__ ehg,
        unsigned short* __restrict__ elg, float* __restrict__ esq,
        int* __restrict__ hist, int* __restrict__ flagcnt,
        float* __restrict__ loss_fix, float* __restrict__ nsum,
        const float* __restrict__ ema_cs, float* __restrict__ dwr, int nrep) {
    const int nsub = blockIdx.x;
    const int t = threadIdx.x;
    // ---- zero dw replicas: block bid zeroes nrep*512 consecutive floats
    {
        const int per = nrep * 512;
        float4* dst = (float4*)(dwr + (size_t)nsub * per);
        const int n4 = per >> 2;
        for (int j = t; j < n4; j += 256) dst[j] = make_float4(0.f, 0.f, 0.f, 0.f);
    }
    if (nsub < 64) {
        if (t < 16) hist[nsub * 16 + t] = 0;
        if (nsub == 0 && t == 16) flagcnt[0] = 0;
        if (nsub == 0 && t == 17) loss_fix[0] = 0.0f;
        #pragma unroll
        for (int it = 0; it < 2; ++it) {
            const int item = it * 256 + t;
            const int kc = item >> 6, lane = item & 63;
            const int quad = lane >> 4, nl = lane & 15;
            const float* ep = emb + (size_t)(nsub * 16 + nl) * Dd + kc * 32 + quad * 8;
            const float4 a = *(const float4*)ep;
            const float4 b4 = *(const float4*)(ep + 4);
            const float v[8] = {a.x, a.y, a.z, a.w, b4.x, b4.y, b4.z, b4.w};
            u16x8 hi, lo;
            #pragma unroll
            for (int j = 0; j < 8; ++j) {
                const unsigned short h = f2bf(v[j]);
                hi[j] = h;
                lo[j] = f2bf(v[j] - bf2f(h));
            }
            const size_t off = ((size_t)(nsub * 8 + kc) * 64 + lane) * 8;
            *(u16x8*)&ehg[off] = hi;
            *(u16x8*)&elg[off] = lo;
        }
        {
            const int nl = t >> 4, seg = t & 15;
            const float* ep = emb + (size_t)(nsub * 16 + nl) * Dd + seg * 16;
            float s = 0.0f;
            #pragma unroll
            for (int j = 0; j < 4; ++j) {
                const float4 v4 = *(const float4*)(ep + j * 4);
                s += v4.x * v4.x + v4.y * v4.y + v4.z * v4.z + v4.w * v4.w;
            }
            #pragma unroll
            for (int d = 1; d < 16; d <<= 1) s += __shfl_xor(s, d);
            if (seg == 0) esq[nsub * 16 + nl] = s;
        }
    } else if (nsub == 64) {
        __shared__ float wred[4];
        const int w = t >> 6, lane = t & 63;
        float s = ema_cs[t] + ema_cs[t + 256] + ema_cs[t + 512] + ema_cs[t + 768];
        #pragma unroll
        for (int d = 32; d > 0; d >>= 1) s += __shfl_xor(s, d);
        if (lane == 0) wred[w] = s;
        __syncthreads();
        if (t == 0)
            nsum[0] = DECAY * (wred[0] + wred[1] + wred[2] + wred[3])
                      + (1.0f - DECAY) * (float)Nn;
    }
}

// ---------------------------------------------------------------------------
// Kernel 2: MFMA distance + top-2 argmin + hist + loss + z_q store + dw.
// (unchanged from R6 — dw last/no trailing barrier, x-replicated atomics)
__global__ __launch_bounds__(256) void dist_kernel(
        const float* __restrict__ z, const unsigned short* __restrict__ ehg,
        const unsigned short* __restrict__ elg, const float* __restrict__ esq,
        const float* __restrict__ emb,
        float* __restrict__ zq, float* __restrict__ dwr, int repmask,
        int* __restrict__ idx_i, float* __restrict__ idx_f,
        int* __restrict__ hist, int* __restrict__ flagcnt,
        int* __restrict__ flaglist, float* __restrict__ flagval,
        float* __restrict__ loss_p) {
    __shared__ __align__(16) unsigned char smem[70656];
    __shared__ int kidx[64];
    unsigned short* zh = (unsigned short*)smem;            // 32KB  [0,32768)
    unsigned short* zl = (unsigned short*)(smem + 32768);  // 32KB  [32768,65536)
    ull* mb   = (ull*)(smem + 65536);                      // 2KB
    ull* ms   = (ull*)(smem + 67584);                      // 2KB
    float* zsqp = (float*)(smem + 69632);                  // 1KB
    float* eldsf = (float*)smem;                           // [64][257] f32; aliases zh/zl/mb/ms (dead when written)

    const int t = threadIdx.x, w = t >> 6, L = t & 63;
    const int quad = L >> 4, lr = L & 15;
    const int m0 = blockIdx.x * 64;
    const int b = m0 >> 10, hw0 = m0 & 1023;

    {
        const int c0 = w * 64;
        const float* zp = z + (size_t)b * 262144 + hw0 + L;
        float s = 0.0f;
        #pragma unroll
        for (int cg = 0; cg < 8; ++cg) {
            float v[8];
            #pragma unroll
            for (int j = 0; j < 8; ++j)
                v[j] = zp[(size_t)(c0 + cg * 8 + j) * 1024];
            u16x8 hi, lo;
            #pragma unroll
            for (int j = 0; j < 8; ++j) {
                s = fmaf(v[j], v[j], s);
                const unsigned short h = f2bf(v[j]);
                hi[j] = h;
                lo[j] = f2bf(v[j] - bf2f(h));
            }
            const int chunk = ((c0 >> 3) + cg) ^ (L & 7);
            *(u16x8*)&zh[L * 256 + chunk * 8] = hi;
            *(u16x8*)&zl[L * 256 + chunk * 8] = lo;
        }
        zsqp[L * 4 + w] = s;
    }
    __syncthreads();

    const unsigned short* ehw = ehg + (size_t)(w * 1024 + L) * 8;
    const unsigned short* elw = elg + (size_t)(w * 1024 + L) * 8;

    unsigned bb[16], ss[16];
    #pragma unroll
    for (int i = 0; i < 16; ++i) { bb[i] = 0xFFFFFFFFu; ss[i] = 0xFFFFFFFFu; }

    bf16x8 Bh[2][2], Bl[2][2];
    #pragma unroll
    for (int ni = 0; ni < 2; ++ni) {
        Bh[0][ni] = *(const bf16x8*)(ehw + (size_t)ni * 4096);
        Bl[0][ni] = *(const bf16x8*)(elw + (size_t)ni * 4096);
    }
    bf16x8 Ah[2][4], Al[2][4];
    #pragma unroll
    for (int mi = 0; mi < 4; ++mi) {
        const int chunk = quad ^ (lr & 7);               // kc = 0
        const int o = (mi * 16 + lr) * 256 + chunk * 8;
        Ah[0][mi] = *(const bf16x8*)&zh[o];
        Al[0][mi] = *(const bf16x8*)&zl[o];
    }

    for (int nt = 0; nt < 8; ++nt) {
        f32x4 acc[4][2];
        #pragma unroll
        for (int mi = 0; mi < 4; ++mi)
            #pragma unroll
            for (int ni = 0; ni < 2; ++ni) acc[mi][ni] = (f32x4){0.f, 0.f, 0.f, 0.f};

        #pragma unroll
        for (int kc = 0; kc < 8; ++kc) {
            const int cur = kc & 1, nxt = cur ^ 1;
            const int nkc = (kc + 1) & 7;
            const int nnt = (kc == 7) ? ((nt + 1) & 7) : nt;
            #pragma unroll
            for (int ni = 0; ni < 2; ++ni) {
                const size_t o = (size_t)nnt * 32768 + (size_t)ni * 4096 + (size_t)nkc * 512;
                Bh[nxt][ni] = *(const bf16x8*)(ehw + o);
                Bl[nxt][ni] = *(const bf16x8*)(elw + o);
            }
            #pragma unroll
            for (int mi = 0; mi < 4; ++mi) {
                const int chunk = (nkc * 4 + quad) ^ (lr & 7);
                const int o = (mi * 16 + lr) * 256 + chunk * 8;
                Ah[nxt][mi] = *(const bf16x8*)&zh[o];
                Al[nxt][mi] = *(const bf16x8*)&zl[o];
            }
            __builtin_amdgcn_s_setprio(1);
            #pragma unroll
            for (int mi = 0; mi < 4; ++mi)
                #pragma unroll
                for (int ni = 0; ni < 2; ++ni) {
                    acc[mi][ni] = __builtin_amdgcn_mfma_f32_16x16x32_bf16(Ah[cur][mi], Bh[cur][ni], acc[mi][ni], 0, 0, 0);
                    acc[mi][ni] = __builtin_amdgcn_mfma_f32_16x16x32_bf16(Ah[cur][mi], Bl[cur][ni], acc[mi][ni], 0, 0, 0);
                    acc[mi][ni] = __builtin_amdgcn_mfma_f32_16x16x32_bf16(Al[cur][mi], Bh[cur][ni], acc[mi][ni], 0, 0, 0);
                }
            __builtin_amdgcn_s_setprio(0);
        }
        const int q0 = nt * 8 + w * 2;
        const float e0b = esq[q0 * 16 + lr] + 512.0f;
        const float e1b = esq[(q0 + 1) * 16 + lr] + 512.0f;
        #pragma unroll
        for (int mi = 0; mi < 4; ++mi)
            #pragma unroll
            for (int reg = 0; reg < 4; ++reg) {
                const int i = mi * 4 + reg;
                #pragma unroll
                for (int ni = 0; ni < 2; ++ni) {
                    const float val = fmaf(-2.0f, acc[mi][ni][reg], ni ? e1b : e0b);
                    const unsigned pk = (__float_as_uint(val) & 0xFFFFFFC0u) | (unsigned)(q0 + ni);
                    const unsigned mx = umax32(bb[i], pk);
                    bb[i] = umin32(bb[i], pk);
                    ss[i] = umin32(ss[i], mx);
                }
            }
    }

    #pragma unroll
    for (int mi = 0; mi < 4; ++mi)
        #pragma unroll
        for (int reg = 0; reg < 4; ++reg) {
            const int i = mi * 4 + reg;
            ull b2 = ((ull)(bb[i] & 0xFFFFFFC0u) << 14) | (ull)((bb[i] & 63u) * 16 + lr);
            ull s2 = ((ull)(ss[i] & 0xFFFFFFC0u) << 14) | (ull)((ss[i] & 63u) * 16 + lr);
            #pragma unroll
            for (int d = 1; d < 16; d <<= 1) {
                const ull ob = __shfl_xor(b2, d);
                const ull os = __shfl_xor(s2, d);
                const ull mx = ob < b2 ? b2 : ob;
                b2 = ob < b2 ? ob : b2;
                const ull ns = os < s2 ? os : s2;
                s2 = mx < ns ? mx : ns;
            }
            if (lr == 0) {
                const int row = mi * 16 + quad * 4 + reg;
                mb[w * 64 + row] = b2;
                ms[w * 64 + row] = s2;
            }
        }
    __syncthreads();

    if (t < 64) {
        ull b2 = mb[t], s2 = ms[t];
        #pragma unroll
        for (int ww = 1; ww < 4; ++ww) {
            const ull ob = mb[ww * 64 + t], os = ms[ww * 64 + t];
            const ull mx = ob < b2 ? b2 : ob;
            b2 = ob < b2 ? ob : b2;
            const ull ns = os < s2 ? os : s2;
            s2 = mx < ns ? mx : ns;
        }
        const int k = (int)(b2 & 16383ull);
        const float v1 = __uint_as_float((unsigned)(b2 >> 14)) - 512.0f;
        const float v2 = __uint_as_float((unsigned)(s2 >> 14)) - 512.0f;
        idx_i[m0 + t] = k;
        idx_f[m0 + t] = (float)k;
        kidx[t] = k;
        atomicAdd(&hist[k], 1);
        if (v2 - v1 < EPSGAP) {
            const int pos = atomicAdd(flagcnt, 1);
            flaglist[pos] = m0 + t;
            flagval[pos] = v1;
        }
        float lp = v1 + zsqp[t * 4] + zsqp[t * 4 + 1] + zsqp[t * 4 + 2] + zsqp[t * 4 + 3];
        #pragma unroll
        for (int d = 32; d > 0; d >>= 1) lp += __shfl_down(lp, d);
        if (t == 0) loss_p[blockIdx.x] = lp;
    }
    __syncthreads();

    // ---- Phase emb-load: the 64 code rows into eldsf[64][257]
    for (int pr = w; pr < 64; pr += 4) {
        const float* er = emb + (size_t)kidx[pr] * Dd;
        #pragma unroll
        for (int g = 0; g < 4; ++g)
            eldsf[pr * 257 + g * 64 + L] = er[g * 64 + L];
    }
    __syncthreads();

    // ---- Phase z_q store: [B,C,HW] layout, coalesced float4 over hw
    {
        const int g = t & 15;
        const int cl = t >> 4;
        float* zqb = zq + (size_t)b * 262144 + hw0 + g * 4;
        #pragma unroll
        for (int pass = 0; pass < 16; ++pass) {
            const int c = pass * 16 + cl;
            float4 v;
            v.x = eldsf[(g * 4 + 0) * 257 + c];
            v.y = eldsf[(g * 4 + 1) * 257 + c];
            v.z = eldsf[(g * 4 + 2) * 257 + c];
            v.w = eldsf[(g * 4 + 3) * 257 + c];
            *(float4*)(zqb + (size_t)c * 1024) = v;
        }
    }

    // ---- Phase dw (LAST, no trailing barrier): z re-read + replicated atomics
    {
        const int c = t;
        const float* zcol = z + (size_t)b * 262144 + (size_t)c * 1024 + hw0;
        float* dwb = dwr + (size_t)(blockIdx.x & repmask) * (Kk * Dd);
        #pragma unroll 4
        for (int p = 0; p < 64; ++p) {
            atomicAdd(&dwb[(size_t)kidx[p] * Dd + c], zcol[p]);
        }
    }
}

// ---------------------------------------------------------------------------
// Kernel 3: exact fp32 re-argmin for flagged points; patches idx/hist/loss,
// dw (replica 0) and the z_q row. (unchanged from R6)
__global__ __launch_bounds__(256) void fixup_kernel(
        const float* __restrict__ z, const float* __restrict__ emb,
        const float* __restrict__ esq, const int* __restrict__ flagcnt,
        const int* __restrict__ flaglist, const float* __restrict__ flagval,
        int* __restrict__ idx_i, float* __restrict__ idx_f,
        int* __restrict__ hist, float* __restrict__ loss_fix,
        float* __restrict__ zq, float* __restrict__ dw) {
    __shared__ float zrow[256];
    __shared__ ull red[256];
    __shared__ int s_pair[2];
    const int t = threadIdx.x;
    const int total = flagcnt[0];
    for (int fi = blockIdx.x; fi < total; fi += 512) {
        const int n = flaglist[fi];
        const int b = n >> 10, hw = n & 1023;
        __syncthreads();
        zrow[t] = z[(size_t)b * 262144 + (size_t)t * 1024 + hw];
        __syncthreads();
        ull best = ~0ull;
        #pragma unroll
        for (int kc = 0; kc < 4; ++kc) {
            const int k = t * 4 + kc;
            const float* ep = emb + (size_t)k * Dd;
            float dot = 0.0f;
            #pragma unroll 8
            for (int c4 = 0; c4 < 64; ++c4) {
                const float4 e4 = *(const float4*)(ep + c4 * 4);
                const float4 z4 = *(const float4*)&zrow[c4 * 4];
                dot = fmaf(z4.x, e4.x, dot);
                dot = fmaf(z4.y, e4.y, dot);
                dot = fmaf(z4.z, e4.z, dot);
                dot = fmaf(z4.w, e4.w, dot);
            }
            const float val = esq[k] - 2.0f * dot;
            const ull pk = ((ull)mono(__float_as_uint(val)) << 32) | (unsigned)k;
            if (pk < best) best = pk;
        }
        red[t] = best;
        __syncthreads();
        for (int s = 128; s > 0; s >>= 1) {
            if (t < s) { if (red[t + s] < red[t]) red[t] = red[t + s]; }
            __syncthreads();
        }
        if (t == 0) {
            const int knew = (int)(unsigned)(red[0] & 0xFFFFFFFFull);
            const float vnew = unmono((unsigned)(red[0] >> 32));
            const int kold = idx_i[n];
            s_pair[0] = kold;
            s_pair[1] = knew;
            if (knew != kold) {
                idx_i[n] = knew;
                idx_f[n] = (float)knew;
                atomicSub(&hist[kold], 1);
                atomicAdd(&hist[knew], 1);
            }
            atomicAdd(loss_fix, vnew - flagval[fi]);
        }
        __syncthreads();
        const int kold = s_pair[0], knew = s_pair[1];
        if (knew != kold) {
            const float zv = zrow[t];
            atomicAdd(&dw[(size_t)kold * Dd + t], -zv);
            atomicAdd(&dw[(size_t)knew * Dd + t], zv);
            zq[(size_t)b * 262144 + (size_t)t * 1024 + hw] = emb[(size_t)knew * Dd + t];
        }
    }
}

// ---------------------------------------------------------------------------
// Kernel 4 (R7): finalize — one block per code k. Computes cs[k] locally
// (nsum precomputed in prep_e; sum(hist)=32768 invariant), sums dw replicas,
// EMA + divide. Block 0 additionally reduces the loss. Replaces scan_fin1 +
// old finalize2.
__global__ __launch_bounds__(256) void finalize2_kernel(
        const float* __restrict__ ema_w, const float* __restrict__ dwr,
        int nrep, const int* __restrict__ hist,
        const float* __restrict__ ema_cs, const float* __restrict__ nsum,
        const float* __restrict__ loss_p, const float* __restrict__ loss_fix,
        float* __restrict__ cs_out, float* __restrict__ loss_out,
        float* __restrict__ new_emb_out, float* __restrict__ new_ema_w_out) {
    const int k = blockIdx.x;
    const int t = threadIdx.x;
    const float n = nsum[0];
    const float csr = ema_cs[k] * DECAY + (1.0f - DECAY) * (float)hist[k];
    const float cs = (csr + EPSV) / (n + (float)Kk * EPSV) * n;
    if (t == 0) cs_out[k] = cs;
    const int i = k * 256 + t;
    float s = 0.0f;
    for (int r = 0; r < nrep; ++r) s += dwr[(size_t)r * (Kk * Dd) + i];
    const float nw = ema_w[i] * DECAY + (1.0f - DECAY) * s;
    new_ema_w_out[i] = nw;
    new_emb_out[i]   = nw / cs;
    if (k == 0) {
        __shared__ float wred[4];
        const int w = t >> 6, lane = t & 63;
        float r2 = loss_p[t] + loss_p[t + 256];
        #pragma unroll
        for (int d = 32; d > 0; d >>= 1) r2 += __shfl_xor(r2, d);
        if (lane == 0) wred[w] = r2;
        __syncthreads();
        if (t == 0)
            loss_out[0] = BETA * (wred[0] + wred[1] + wred[2] + wred[3]
                                  + loss_fix[0]) / (float)ZELEM;
    }
}

// ---------------------------------------------------------------------------
extern "C" void kernel_launch(void* const* d_in, const int* in_sizes, int n_in,
                              void* d_out, int out_size, void* d_ws, size_t ws_size,
                              hipStream_t stream) {
    const float* z      = (const float*)d_in[0];
    const float* emb    = (const float*)d_in[1];
    const float* ema_cs = (const float*)d_in[2];
    const float* ema_w  = (const float*)d_in[3];

    float* out = (float*)d_out;
    float* zq_out        = out;                 // 8388608 (z_q written directly by dist)
    float* idx_out_f     = out + 8388608;       // 32768
    float* loss_out      = out + 8421376;       // 1
    float* new_emb_out   = out + 8421377;       // 262144
    float* cs_out        = out + 8683521;       // 1024
    float* new_ema_w_out = out + 8684545;       // 262144

    int*   idx_i    = (int*)d_ws;                    // 32768
    int*   flagcnt  = idx_i + 32768;                 // 16
    float* loss_fix = (float*)(flagcnt + 16);        // 16
    int*   flaglist = (int*)(loss_fix + 16);         // 32768
    float* flagval  = (float*)(flaglist + 32768);    // 32768
    int*   hist     = (int*)(flagval + 32768);       // 1024
    float* esq      = (float*)(hist + 1024);         // 1024
    float* loss_p   = esq + 1024;                    // 512
    float* nsum     = loss_p + 512;                  // 16
    unsigned short* ehg = (unsigned short*)(nsum + 16);     // 262144 shorts
    unsigned short* elg = ehg + 262144;                     // 262144 shorts
    // dw replicas: after elg, 256B-aligned
    size_t dwr_off = ((size_t)((char*)(elg + 262144) - (char*)d_ws) + 255) & ~(size_t)255;
    float* dwr = (float*)((char*)d_ws + dwr_off);
    const size_t repbytes = (size_t)Kk * Dd * 4;     // 1MB per replica
    size_t rem = (ws_size > dwr_off) ? ws_size - dwr_off : 0;
    int nrep = 1;
    while (nrep < 8 && (size_t)(nrep * 2) * repbytes <= rem) nrep <<= 1;

    prep_e_kernel<<<512, 256, 0, stream>>>(emb, ehg, elg, esq, hist, flagcnt,
                                           loss_fix, nsum, ema_cs, dwr, nrep);
    dist_kernel<<<Nn / 64, 256, 0, stream>>>(z, ehg, elg, esq, emb, zq_out,
                                             dwr, nrep - 1, idx_i, idx_out_f,
                                             hist, flagcnt, flaglist, flagval,
                                             loss_p);
    fixup_kernel<<<512, 256, 0, stream>>>(z, emb, esq, flagcnt, flaglist,
                                          flagval, idx_i, idx_out_f, hist,
                                          loss_fix, zq_out, dwr);
    finalize2_kernel<<<Kk, 256, 0, stream>>>(ema_w, dwr, nrep, hist, ema_cs,
                                             nsum, loss_p, loss_fix, cs_out,
                                             loss_out, new_emb_out,
                                             new_ema_w_out);
}